// Round 12
// baseline (868.719 us; speedup 1.0000x reference)
//
#include <hip/hip_runtime.h>

#define DHC 128
#define BSHIFT 8
#define BSIZE 256  // dst nodes per bucket

typedef __attribute__((ext_vector_type(8))) __bf16 bf16x8;
typedef __attribute__((ext_vector_type(8))) unsigned short ushort8;
typedef __attribute__((ext_vector_type(4))) float floatx4;
typedef __attribute__((ext_vector_type(4))) int intx4;
typedef __attribute__((ext_vector_type(4))) unsigned int uintx4;

__device__ inline unsigned short f2bf(float f) {
    unsigned int u = __float_as_uint(f);
    return (unsigned short)((u + 0x7FFFu + ((u >> 16) & 1u)) >> 16);
}
__device__ inline float bf2f_lo(unsigned int v) { return __uint_as_float(v << 16); }
__device__ inline float bf2f_hi(unsigned int v) { return __uint_as_float(v & 0xFFFF0000u); }

// ---------------- graph prep: bucket sort by dst>>8, then per-bucket padded CSR ----------------

// hist blocks [0, eb); wconv blocks [eb, eb+192): 3x W[128k][128n] fp32 -> WT[n][k] bf16
__global__ __launch_bounds__(256) void bucket_hist(const int* __restrict__ dst,
                                                   int* __restrict__ bcount, int e, int eb,
                                                   const float* __restrict__ W1,
                                                   const float* __restrict__ W2,
                                                   const float* __restrict__ W3,
                                                   unsigned short* __restrict__ WTall,
                                                   unsigned short* __restrict__ dumA,
                                                   unsigned short* __restrict__ dumB) {
    if ((int)blockIdx.x >= eb) {
        int bb = (int)blockIdx.x - eb;
        if (bb == 0 && threadIdx.x < 128) {
            dumA[threadIdx.x] = 0;
            dumB[threadIdx.x] = 0;
        }
        int idx = bb * 256 + threadIdx.x;  // 3*16384
        int wsel = idx >> 14;
        int i = idx & 16383;
        int nn = i >> 7, k = i & 127;
        const float* W = (wsel == 0) ? W1 : (wsel == 1) ? W2 : W3;
        WTall[idx] = f2bf(W[k * 128 + nn]);
        return;
    }
    __shared__ int h[512];
    for (int i = threadIdx.x; i < 512; i += 256) h[i] = 0;
    __syncthreads();
    int base = blockIdx.x * 4096 + threadIdx.x;
#pragma unroll
    for (int j = 0; j < 16; j++) {
        int i = base + j * 256;
        if (i < e) atomicAdd(&h[dst[i] >> BSHIFT], 1);
    }
    __syncthreads();
    for (int i = threadIdx.x; i < 512; i += 256)
        if (h[i]) atomicAdd(&bcount[i], h[i]);
}

__global__ void bucket_scan(const int* __restrict__ bcount, int* __restrict__ bbase,
                            int* __restrict__ bcur, int nb, int e) {
    __shared__ int s[512];
    int t = threadIdx.x;
    s[t] = (t < nb) ? bcount[t] : 0;
    __syncthreads();
    for (int off = 1; off < 512; off <<= 1) {
        int add = (t >= off) ? s[t - off] : 0;
        __syncthreads();
        s[t] += add;
        __syncthreads();
    }
    if (t < nb) {
        int ex = (t == 0) ? 0 : s[t - 1];
        bbase[t] = ex;
        bcur[t] = ex;
    }
    if (t == 0) bbase[nb] = e;
}

// scatter edges into bucket regions; packed entry = src | (dst_local << 20)
__global__ __launch_bounds__(256) void bucket_scatter(const int* __restrict__ src,
                                                      const int* __restrict__ dst,
                                                      int* __restrict__ bcur,
                                                      unsigned int* __restrict__ ebuf, int e) {
    __shared__ int h[512];
    __shared__ int rsv[512];
    for (int i = threadIdx.x; i < 512; i += 256) h[i] = 0;
    __syncthreads();
    int base = blockIdx.x * 4096 + threadIdx.x;
    int sreg[16], dreg[16];
#pragma unroll
    for (int j = 0; j < 16; j++) {
        int i = base + j * 256;
        if (i < e) {
            sreg[j] = src[i];
            dreg[j] = dst[i];
            atomicAdd(&h[dreg[j] >> BSHIFT], 1);
        } else {
            dreg[j] = -1;
        }
    }
    __syncthreads();
    for (int i = threadIdx.x; i < 512; i += 256) {
        int c = h[i];
        rsv[i] = c ? atomicAdd(&bcur[i], c) : 0;
        h[i] = 0;
    }
    __syncthreads();
#pragma unroll
    for (int j = 0; j < 16; j++) {
        if (dreg[j] >= 0) {
            int b = dreg[j] >> BSHIFT;
            int pos = rsv[b] + atomicAdd(&h[b], 1);
            ebuf[pos] = (unsigned int)sreg[j] | ((unsigned int)(dreg[j] & (BSIZE - 1)) << 20);
        }
    }
}

// per-bucket degrees -> degs[], dinv[], padded-degree sum per bucket
__global__ __launch_bounds__(256) void bucket_dega(const unsigned int* __restrict__ ebuf,
                                                   const int* __restrict__ bbase,
                                                   int* __restrict__ degs,
                                                   int* __restrict__ pbsum,
                                                   float* __restrict__ dinv, int n) {
    __shared__ int ldeg[256];
    __shared__ int red[256];
    int b = blockIdx.x, t = threadIdx.x;
    int beg = bbase[b], end = bbase[b + 1];
    ldeg[t] = 0;
    __syncthreads();
    for (int i = beg + t; i < end; i += 256) atomicAdd(&ldeg[ebuf[i] >> 20], 1);
    __syncthreads();
    int node = (b << BSHIFT) + t;
    int deg = ldeg[t];
    int pdeg = (deg + 7) & ~7;  // pad row to multiple of 8
    if (node < n) {
        degs[node] = deg;
        dinv[node] = rsqrtf((float)(deg + 1));
    } else {
        pdeg = 0;
    }
    red[t] = pdeg;
    __syncthreads();
    for (int off = 128; off > 0; off >>= 1) {
        if (t < off) red[t] += red[t + off];
        __syncthreads();
    }
    if (t == 0) pbsum[b] = red[0];
}

// exclusive scan of padded bucket sums -> pbase; set row_ptr[n]
__global__ void pscan(const int* __restrict__ pbsum, int* __restrict__ pbase,
                      int* __restrict__ row_ptr, int nb, int n) {
    __shared__ int s[512];
    int t = threadIdx.x;
    s[t] = (t < nb) ? pbsum[t] : 0;
    __syncthreads();
    for (int off = 1; off < 512; off <<= 1) {
        int add = (t >= off) ? s[t - off] : 0;
        __syncthreads();
        s[t] += add;
        __syncthreads();
    }
    if (t < nb) pbase[t] = (t == 0) ? 0 : s[t - 1];
    if (t == 0) {
        pbase[nb] = s[nb - 1];
        row_ptr[n] = s[nb - 1];
    }
}

// padded per-bucket CSR build: row_ptr (8-aligned rows), scatter src, dummy-fill pad slots
__global__ __launch_bounds__(256) void bucket_csr(const unsigned int* __restrict__ ebuf,
                                                  const int* __restrict__ bbase,
                                                  const int* __restrict__ pbase,
                                                  const int* __restrict__ degs,
                                                  int* __restrict__ row_ptr,
                                                  int* __restrict__ csr, int n) {
    __shared__ int lcur[256];
    __shared__ int lscan[256];
    int b = blockIdx.x, t = threadIdx.x;
    int beg = bbase[b], end = bbase[b + 1];
    int node = (b << BSHIFT) + t;
    int deg = (node < n) ? degs[node] : 0;
    int pdeg = (deg + 7) & ~7;
    lscan[t] = pdeg;
    __syncthreads();
    for (int off = 1; off < 256; off <<= 1) {
        int add = (t >= off) ? lscan[t - off] : 0;
        __syncthreads();
        lscan[t] += add;
        __syncthreads();
    }
    int rp = pbase[b] + lscan[t] - pdeg;  // exclusive
    if (node < n) row_ptr[node] = rp;
    lcur[t] = rp;
    __syncthreads();
    for (int i = beg + t; i < end; i += 256) {
        unsigned int p = ebuf[i];
        int pos = atomicAdd(&lcur[p >> 20], 1);
        csr[pos] = (int)(p & 0xFFFFFu);
    }
    __syncthreads();
    for (int j = deg; j < pdeg; j++) csr[rp + j] = n;  // dummy (zero row)
}

// ---------------- MFMA bf16 GEMM: out = A[N,128] @ W, B staged in LDS ----------------
// MODE 0: outB = bf16(dinv[r] * (A@W))  (pre-scaled rows for the aggregation)
// MODE 2: fused BN-folded classifier + output projection; bias2 (= bc) added to bias
template <int MODE, int AF32>
__global__ __launch_bounds__(256, 4) void gemm_k(const void* __restrict__ Avoid,
                                                 const unsigned short* __restrict__ WT,
                                                 const float* __restrict__ bias,
                                                 const float* __restrict__ bias2,
                                                 unsigned short* __restrict__ outB,
                                                 float* __restrict__ outF,
                                                 const float* __restrict__ Wr,
                                                 const float* __restrict__ br,
                                                 const float* __restrict__ dinvp, int n) {
    __shared__ unsigned short Ws[32 * 512];
    {
        for (int c = threadIdx.x; c < 2048; c += 256) {
            int f = c >> 6;
            int l = c & 63;
            int ks = f >> 3, ct = f & 7;
            int nn = ct * 16 + (l & 15);
            int kb = ks * 32 + (l >> 4) * 8;
            *(uint4*)(&Ws[c * 8]) = *(const uint4*)(&WT[nn * 128 + kb]);
        }
    }
    __syncthreads();
    const int wave = threadIdx.x >> 6;
    const int lane = threadIdx.x & 63;
    const int rowbase = blockIdx.x * 128 + wave * 32;
    const int m = lane & 15;
    const int kq = lane >> 4;  // 0..3

    floatx4 acc[2][8];
#pragma unroll
    for (int rt = 0; rt < 2; rt++)
#pragma unroll
        for (int ct = 0; ct < 8; ct++) acc[rt][ct] = (floatx4){0.f, 0.f, 0.f, 0.f};

    const int r0 = min(rowbase + m, n - 1);
    const int r1 = min(rowbase + 16 + m, n - 1);

#pragma unroll
    for (int ks = 0; ks < 4; ks++) {
        const int kb = ks * 32 + kq * 8;
        bf16x8 a0, a1;
        if (AF32) {
            const float* Af = (const float*)Avoid;
            float4 f00 = *(const float4*)(Af + (size_t)r0 * 128 + kb);
            float4 f01 = *(const float4*)(Af + (size_t)r0 * 128 + kb + 4);
            float4 f10 = *(const float4*)(Af + (size_t)r1 * 128 + kb);
            float4 f11 = *(const float4*)(Af + (size_t)r1 * 128 + kb + 4);
            ushort8 u0, u1;
            u0[0] = f2bf(f00.x); u0[1] = f2bf(f00.y); u0[2] = f2bf(f00.z); u0[3] = f2bf(f00.w);
            u0[4] = f2bf(f01.x); u0[5] = f2bf(f01.y); u0[6] = f2bf(f01.z); u0[7] = f2bf(f01.w);
            u1[0] = f2bf(f10.x); u1[1] = f2bf(f10.y); u1[2] = f2bf(f10.z); u1[3] = f2bf(f10.w);
            u1[4] = f2bf(f11.x); u1[5] = f2bf(f11.y); u1[6] = f2bf(f11.z); u1[7] = f2bf(f11.w);
            a0 = __builtin_bit_cast(bf16x8, u0);
            a1 = __builtin_bit_cast(bf16x8, u1);
        } else {
            const unsigned short* Ab = (const unsigned short*)Avoid;
            a0 = __builtin_bit_cast(bf16x8, *(const ushort8*)(Ab + (size_t)r0 * 128 + kb));
            a1 = __builtin_bit_cast(bf16x8, *(const ushort8*)(Ab + (size_t)r1 * 128 + kb));
        }
#pragma unroll
        for (int ct = 0; ct < 8; ct++) {
            bf16x8 bfr = __builtin_bit_cast(bf16x8,
                *(const ushort8*)(&Ws[(ks * 8 + ct) * 512 + lane * 8]));
            acc[0][ct] = __builtin_amdgcn_mfma_f32_16x16x32_bf16(a0, bfr, acc[0][ct], 0, 0, 0);
            acc[1][ct] = __builtin_amdgcn_mfma_f32_16x16x32_bf16(a1, bfr, acc[1][ct], 0, 0, 0);
        }
    }

    if (MODE == 0) {
#pragma unroll
        for (int rt = 0; rt < 2; rt++) {
#pragma unroll
            for (int i = 0; i < 4; i++) {
                int r = rowbase + rt * 16 + kq * 4 + i;
                if (r < n) {
                    float dv = dinvp[r];
#pragma unroll
                    for (int ct = 0; ct < 8; ct++) {
                        int col = ct * 16 + m;
                        outB[(size_t)r * 128 + col] = f2bf(acc[rt][ct][i] * dv);
                    }
                }
            }
        }
    } else {
        float bcv[8], wr0[8], wr1[8];
#pragma unroll
        for (int ct = 0; ct < 8; ct++) {
            int col = ct * 16 + m;
            bcv[ct] = bias[col] + bias2[col];
            float2 wv = ((const float2*)Wr)[col];
            wr0[ct] = wv.x;
            wr1[ct] = wv.y;
        }
        float br0 = br[0], br1 = br[1];
#pragma unroll
        for (int rt = 0; rt < 2; rt++) {
#pragma unroll
            for (int i = 0; i < 4; i++) {
                float p0 = 0.f, p1 = 0.f;
#pragma unroll
                for (int ct = 0; ct < 8; ct++) {
                    float v = fmaxf(acc[rt][ct][i] + bcv[ct], 0.f);
                    p0 = fmaf(v, wr0[ct], p0);
                    p1 = fmaf(v, wr1[ct], p1);
                }
#pragma unroll
                for (int mk = 1; mk < 16; mk <<= 1) {
                    p0 += __shfl_xor(p0, mk);
                    p1 += __shfl_xor(p1, mk);
                }
                int r = rowbase + rt * 16 + kq * 4 + i;
                if (m == 0 && r < n) ((float2*)outF)[r] = make_float2(p0 + br0, p1 + br1);
            }
        }
    }
}

// ---------------- XCD-sliced CSR gather aggregation: 8 feature slices x 2 lanes/node ----------------
// Slice s = blockIdx & 7 covers channels [s*16, s*16+16) = 32B/node -> slice working set
// N*32B = 3.2 MB < 4 MB per-XCD L2. With the round-robin blockIdx->XCD mapping, each XCD
// gathers ONLY from its resident slice -> L2-hit gathers instead of L3/HBM fabric traffic.
// CSR is re-read by all 8 slices; loaded nontemporal so it cannot evict the slice. Output
// stored nontemporal (next consumer streams it). Same bytes/edge as before (256B across 8
// slices); 2 lanes x uint4 per node.
#define ACC8(v)                                          \
    a[0] += bf2f_lo((v).x); a[1] += bf2f_hi((v).x);      \
    a[2] += bf2f_lo((v).y); a[3] += bf2f_hi((v).y);      \
    a[4] += bf2f_lo((v).z); a[5] += bf2f_hi((v).z);      \
    a[6] += bf2f_lo((v).w); a[7] += bf2f_hi((v).w);

__global__ __launch_bounds__(256) void agg_k(const unsigned short* __restrict__ hS,
                                             const int* __restrict__ csr,
                                             const int* __restrict__ row_ptr,
                                             const float* __restrict__ dinv,
                                             const float* __restrict__ bias,
                                             unsigned short* __restrict__ out, int n) {
    const int slice = blockIdx.x & 7;
    const int node = (blockIdx.x >> 3) * 128 + (threadIdx.x >> 1);
    const int so = slice * 2 + (threadIdx.x & 1);  // uint4 offset within row, [0,16)
    if (node >= n) return;
    const uint4* h4 = (const uint4*)hS;
    uint4 vs = h4[(size_t)node * 16 + so];  // self contribution (slice-resident)
    int beg = row_ptr[node], pend = row_ptr[node + 1];
    float dd = dinv[node];

    float a[8];
    a[0] = bf2f_lo(vs.x); a[1] = bf2f_hi(vs.x);
    a[2] = bf2f_lo(vs.y); a[3] = bf2f_hi(vs.y);
    a[4] = bf2f_lo(vs.z); a[5] = bf2f_hi(vs.z);
    a[6] = bf2f_lo(vs.w); a[7] = bf2f_hi(vs.w);

    const intx4* cp = (const intx4*)(csr + beg);  // beg multiple of 8 -> 16B aligned
    int nc = (pend - beg) >> 3;                   // chunks of 8 edges (dummy-padded -> row N zeros)
    for (int k = 0; k < nc; k++) {
        intx4 i0 = __builtin_nontemporal_load(cp + 2 * k);      // both lanes same addr (broadcast)
        intx4 i1 = __builtin_nontemporal_load(cp + 2 * k + 1);
        uint4 v0 = h4[(size_t)(unsigned)i0.x * 16 + so];
        uint4 v1 = h4[(size_t)(unsigned)i0.y * 16 + so];
        uint4 v2 = h4[(size_t)(unsigned)i0.z * 16 + so];
        uint4 v3 = h4[(size_t)(unsigned)i0.w * 16 + so];
        uint4 v4 = h4[(size_t)(unsigned)i1.x * 16 + so];
        uint4 v5 = h4[(size_t)(unsigned)i1.y * 16 + so];
        uint4 v6 = h4[(size_t)(unsigned)i1.z * 16 + so];
        uint4 v7 = h4[(size_t)(unsigned)i1.w * 16 + so];
        ACC8(v0); ACC8(v1); ACC8(v2); ACC8(v3);
        ACC8(v4); ACC8(v5); ACC8(v6); ACC8(v7);
    }

    float4 b0 = ((const float4*)bias)[so * 2];
    float4 b1 = ((const float4*)bias)[so * 2 + 1];
    uintx4 o;
    o.x = (unsigned int)f2bf(fmaxf(fmaf(dd, a[0], b0.x), 0.f)) |
          ((unsigned int)f2bf(fmaxf(fmaf(dd, a[1], b0.y), 0.f)) << 16);
    o.y = (unsigned int)f2bf(fmaxf(fmaf(dd, a[2], b0.z), 0.f)) |
          ((unsigned int)f2bf(fmaxf(fmaf(dd, a[3], b0.w), 0.f)) << 16);
    o.z = (unsigned int)f2bf(fmaxf(fmaf(dd, a[4], b1.x), 0.f)) |
          ((unsigned int)f2bf(fmaxf(fmaf(dd, a[5], b1.y), 0.f)) << 16);
    o.w = (unsigned int)f2bf(fmaxf(fmaf(dd, a[6], b1.z), 0.f)) |
          ((unsigned int)f2bf(fmaxf(fmaf(dd, a[7], b1.w), 0.f)) << 16);
    __builtin_nontemporal_store(o, (uintx4*)out + (size_t)node * 16 + so);
}

// ---------------- BN stats (per-channel sum / sumsq) over bf16 h ----------------
__global__ __launch_bounds__(256) void bn_stats(const unsigned short* __restrict__ h,
                                                float* __restrict__ gsum,
                                                float* __restrict__ gsumsq, int n) {
    __shared__ float red[4][256];
    int l = threadIdx.x & 63;
    int rs = threadIdx.x >> 6;
    float s0 = 0.f, s1 = 0.f, q0 = 0.f, q1 = 0.f;
    for (int r = blockIdx.x * 4 + rs; r < n; r += gridDim.x * 4) {
        unsigned int v = *(const unsigned int*)(h + (size_t)r * 128 + l * 2);
        float a = bf2f_lo(v), b = bf2f_hi(v);
        s0 += a;
        s1 += b;
        q0 = fmaf(a, a, q0);
        q1 = fmaf(b, b, q1);
    }
    red[0][threadIdx.x] = s0;
    red[1][threadIdx.x] = s1;
    red[2][threadIdx.x] = q0;
    red[3][threadIdx.x] = q1;
    __syncthreads();
    if (threadIdx.x < 64) {
        float S0 = 0.f, S1 = 0.f, Q0 = 0.f, Q1 = 0.f;
#pragma unroll
        for (int j = 0; j < 4; j++) {
            S0 += red[0][j * 64 + l];
            S1 += red[1][j * 64 + l];
            Q0 += red[2][j * 64 + l];
            Q1 += red[3][j * 64 + l];
        }
        atomicAdd(&gsum[2 * l + 0], S0);
        atomicAdd(&gsum[2 * l + 1], S1);
        atomicAdd(&gsumsq[2 * l + 0], Q0);
        atomicAdd(&gsumsq[2 * l + 1], Q1);
    }
}

// ---------------- fused BN-finalize + fold into Wc ----------------
__global__ __launch_bounds__(256) void wcfold(const float* __restrict__ Wc,
                                              const float* __restrict__ gsum,
                                              const float* __restrict__ gsumsq,
                                              const float* __restrict__ gamma,
                                              const float* __restrict__ beta,
                                              unsigned short* __restrict__ WcT,
                                              float* __restrict__ bcP, float invN) {
    __shared__ float scS[128], shS[128];
    if (threadIdx.x < 128) {
        int j = threadIdx.x;
        float mu = gsum[j] * invN;
        float var = gsumsq[j] * invN - mu * mu;
        float sc = gamma[j] * rsqrtf(var + 1e-5f);
        scS[j] = sc;
        shS[j] = beta[j] - mu * sc;
    }
    __syncthreads();
    int idx = blockIdx.x * 256 + threadIdx.x;  // 16384; j inner -> coalesced Wc reads
    int j = idx & 127, k = idx >> 7;
    float w = Wc[k * 128 + j];
    WcT[j * 128 + k] = f2bf(scS[k] * w);
    atomicAdd(&bcP[j], shS[k] * w);
}

// ---------------- host ----------------

extern "C" void kernel_launch(void* const* d_in, const int* in_sizes, int n_in,
                              void* d_out, int out_size, void* d_ws, size_t ws_size,
                              hipStream_t stream) {
    const float* x = (const float*)d_in[0];
    const int* ei = (const int*)d_in[1];
    const float* W1 = (const float*)d_in[2];
    const float* b1 = (const float*)d_in[3];
    const float* W2 = (const float*)d_in[4];
    const float* b2 = (const float*)d_in[5];
    const float* W3 = (const float*)d_in[6];
    const float* b3 = (const float*)d_in[7];
    const float* gamma = (const float*)d_in[8];
    const float* beta = (const float*)d_in[9];
    const float* Wc = (const float*)d_in[10];
    const float* bc = (const float*)d_in[11];
    const float* Wr = (const float*)d_in[12];
    const float* br = (const float*)d_in[13];
    float* out = (float*)d_out;

    const int N = in_sizes[0] / DHC;
    const int E = in_sizes[1] / 2;
    const int* srcIdx = ei;
    const int* dstIdx = ei + E;
    const int NB = (N + BSIZE - 1) >> BSHIFT;

    char* w = (char*)d_ws;
    size_t off = 0;
    auto alloc = [&](size_t bytes) -> void* {
        void* p = w + off;
        off += (bytes + 255) & ~(size_t)255;
        return p;
    };
    // +1 dummy row (zeros) on each activation buffer for padded edges
    unsigned short* bufA = (unsigned short*)alloc((size_t)(N + 1) * DHC * 2);
    unsigned short* bufB = (unsigned short*)alloc((size_t)(N + 1) * DHC * 2);
    unsigned int* ebuf = (unsigned int*)alloc((size_t)E * 4);
    // padded CSR: up to E + 7 per node, +16 ints slack
    int* csr_src = (int*)alloc(((size_t)E + 8 * (size_t)N + 16) * 4);
    int* row_ptr = (int*)alloc((size_t)(N + 1) * 4);
    float* dinv = (float*)alloc((size_t)N * 4);
    int* degs = (int*)alloc((size_t)N * 4);
    // zeroed region: bcount[512] ++ stats[256] ++ bcP[128] — one memset
    int* bcount = (int*)alloc(512 * 4 + 256 * 4 + 128 * 4);
    float* stats = (float*)(bcount + 512);
    float* gsum = stats;
    float* gsumsq = stats + 128;
    float* bcP = stats + 256;
    int* bbase = (int*)alloc(513 * 4);
    int* bcur = (int*)alloc(512 * 4);
    int* pbsum = (int*)alloc(512 * 4);
    int* pbase = (int*)alloc(513 * 4);
    unsigned short* WTall = (unsigned short*)alloc((size_t)3 * 16384 * 2);
    unsigned short* WT1 = WTall;
    unsigned short* WT2 = WTall + 16384;
    unsigned short* WT3 = WTall + 32768;
    unsigned short* WcT = (unsigned short*)alloc(16384 * 2);
    (void)ws_size; (void)n_in; (void)out_size;

    hipMemsetAsync(bcount, 0, 512 * 4 + 256 * 4 + 128 * 4, stream);

    const int EB = (E + 4095) / 4096;
    bucket_hist<<<EB + 192, 256, 0, stream>>>(dstIdx, bcount, E, EB, W1, W2, W3, WTall,
                                              bufA + (size_t)N * DHC, bufB + (size_t)N * DHC);
    bucket_scan<<<1, 512, 0, stream>>>(bcount, bbase, bcur, NB, E);
    bucket_scatter<<<EB, 256, 0, stream>>>(srcIdx, dstIdx, bcur, ebuf, E);
    bucket_dega<<<NB, 256, 0, stream>>>(ebuf, bbase, degs, pbsum, dinv, N);
    pscan<<<1, 512, 0, stream>>>(pbsum, pbase, row_ptr, NB, N);
    bucket_csr<<<NB, 256, 0, stream>>>(ebuf, bbase, pbase, degs, row_ptr, csr_src, N);

    const int gemmBlocks = (N + 127) / 128;
    const int aggBlocks = ((N + 127) / 128) * 8;  // 8 XCD feature slices

    // layer 1 (A = x fp32, converted in-flight); gemm writes dinv-prescaled rows
    gemm_k<0, 1><<<gemmBlocks, 256, 0, stream>>>(x, WT1, nullptr, nullptr, bufB, nullptr, nullptr, nullptr, dinv, N);
    agg_k<<<aggBlocks, 256, 0, stream>>>(bufB, csr_src, row_ptr, dinv, b1, bufA, N);
    // layer 2
    gemm_k<0, 0><<<gemmBlocks, 256, 0, stream>>>(bufA, WT2, nullptr, nullptr, bufB, nullptr, nullptr, nullptr, dinv, N);
    agg_k<<<aggBlocks, 256, 0, stream>>>(bufB, csr_src, row_ptr, dinv, b2, bufA, N);
    // layer 3
    gemm_k<0, 0><<<gemmBlocks, 256, 0, stream>>>(bufA, WT3, nullptr, nullptr, bufB, nullptr, nullptr, nullptr, dinv, N);
    agg_k<<<aggBlocks, 256, 0, stream>>>(bufB, csr_src, row_ptr, dinv, b3, bufA, N);

    // batchnorm stats + fused finalize/fold + classifier GEMM fused with output projection
    bn_stats<<<256, 256, 0, stream>>>(bufA, gsum, gsumsq, N);
    wcfold<<<64, 256, 0, stream>>>(Wc, gsum, gsumsq, gamma, beta, WcT, bcP, 1.0f / (float)N);
    gemm_k<2, 0><<<gemmBlocks, 256, 0, stream>>>(bufA, WcT, bcP, bc, nullptr, out, Wr, br, dinv, N);
}

// Round 13
// 442.211 us; speedup vs baseline: 1.9645x; 1.9645x over previous
//
#include <hip/hip_runtime.h>

#define DHC 128
#define BSHIFT 8
#define BSIZE 256  // dst nodes per bucket

typedef __attribute__((ext_vector_type(8))) __bf16 bf16x8;
typedef __attribute__((ext_vector_type(8))) unsigned short ushort8;
typedef __attribute__((ext_vector_type(4))) float floatx4;

__device__ inline unsigned short f2bf(float f) {
    unsigned int u = __float_as_uint(f);
    return (unsigned short)((u + 0x7FFFu + ((u >> 16) & 1u)) >> 16);
}
__device__ inline float bf2f_lo(unsigned int v) { return __uint_as_float(v << 16); }
__device__ inline float bf2f_hi(unsigned int v) { return __uint_as_float(v & 0xFFFF0000u); }

// ---------------- graph prep: bucket sort by dst>>8, then per-bucket padded CSR ----------------

// hist blocks [0, eb); wconv blocks [eb, eb+192): 3x W[128k][128n] fp32 -> WT[n][k] bf16
__global__ __launch_bounds__(256) void bucket_hist(const int* __restrict__ dst,
                                                   int* __restrict__ bcount, int e, int eb,
                                                   const float* __restrict__ W1,
                                                   const float* __restrict__ W2,
                                                   const float* __restrict__ W3,
                                                   unsigned short* __restrict__ WTall,
                                                   unsigned short* __restrict__ dumA,
                                                   unsigned short* __restrict__ dumB) {
    if ((int)blockIdx.x >= eb) {
        int bb = (int)blockIdx.x - eb;
        if (bb == 0 && threadIdx.x < 128) {
            dumA[threadIdx.x] = 0;
            dumB[threadIdx.x] = 0;
        }
        int idx = bb * 256 + threadIdx.x;  // 3*16384
        int wsel = idx >> 14;
        int i = idx & 16383;
        int nn = i >> 7, k = i & 127;
        const float* W = (wsel == 0) ? W1 : (wsel == 1) ? W2 : W3;
        WTall[idx] = f2bf(W[k * 128 + nn]);
        return;
    }
    __shared__ int h[512];
    for (int i = threadIdx.x; i < 512; i += 256) h[i] = 0;
    __syncthreads();
    int base = blockIdx.x * 4096 + threadIdx.x;
#pragma unroll
    for (int j = 0; j < 16; j++) {
        int i = base + j * 256;
        if (i < e) atomicAdd(&h[dst[i] >> BSHIFT], 1);
    }
    __syncthreads();
    for (int i = threadIdx.x; i < 512; i += 256)
        if (h[i]) atomicAdd(&bcount[i], h[i]);
}

__global__ void bucket_scan(const int* __restrict__ bcount, int* __restrict__ bbase,
                            int* __restrict__ bcur, int nb, int e) {
    __shared__ int s[512];
    int t = threadIdx.x;
    s[t] = (t < nb) ? bcount[t] : 0;
    __syncthreads();
    for (int off = 1; off < 512; off <<= 1) {
        int add = (t >= off) ? s[t - off] : 0;
        __syncthreads();
        s[t] += add;
        __syncthreads();
    }
    if (t < nb) {
        int ex = (t == 0) ? 0 : s[t - 1];
        bbase[t] = ex;
        bcur[t] = ex;
    }
    if (t == 0) bbase[nb] = e;
}

// scatter edges into bucket regions; packed entry = src | (dst_local << 20)
__global__ __launch_bounds__(256) void bucket_scatter(const int* __restrict__ src,
                                                      const int* __restrict__ dst,
                                                      int* __restrict__ bcur,
                                                      unsigned int* __restrict__ ebuf, int e) {
    __shared__ int h[512];
    __shared__ int rsv[512];
    for (int i = threadIdx.x; i < 512; i += 256) h[i] = 0;
    __syncthreads();
    int base = blockIdx.x * 4096 + threadIdx.x;
    int sreg[16], dreg[16];
#pragma unroll
    for (int j = 0; j < 16; j++) {
        int i = base + j * 256;
        if (i < e) {
            sreg[j] = src[i];
            dreg[j] = dst[i];
            atomicAdd(&h[dreg[j] >> BSHIFT], 1);
        } else {
            dreg[j] = -1;
        }
    }
    __syncthreads();
    for (int i = threadIdx.x; i < 512; i += 256) {
        int c = h[i];
        rsv[i] = c ? atomicAdd(&bcur[i], c) : 0;
        h[i] = 0;
    }
    __syncthreads();
#pragma unroll
    for (int j = 0; j < 16; j++) {
        if (dreg[j] >= 0) {
            int b = dreg[j] >> BSHIFT;
            int pos = rsv[b] + atomicAdd(&h[b], 1);
            ebuf[pos] = (unsigned int)sreg[j] | ((unsigned int)(dreg[j] & (BSIZE - 1)) << 20);
        }
    }
}

// per-bucket degrees -> degs[], dinv[], padded-degree sum per bucket
__global__ __launch_bounds__(256) void bucket_dega(const unsigned int* __restrict__ ebuf,
                                                   const int* __restrict__ bbase,
                                                   int* __restrict__ degs,
                                                   int* __restrict__ pbsum,
                                                   float* __restrict__ dinv, int n) {
    __shared__ int ldeg[256];
    __shared__ int red[256];
    int b = blockIdx.x, t = threadIdx.x;
    int beg = bbase[b], end = bbase[b + 1];
    ldeg[t] = 0;
    __syncthreads();
    for (int i = beg + t; i < end; i += 256) atomicAdd(&ldeg[ebuf[i] >> 20], 1);
    __syncthreads();
    int node = (b << BSHIFT) + t;
    int deg = ldeg[t];
    int pdeg = (deg + 7) & ~7;  // pad row to multiple of 8
    if (node < n) {
        degs[node] = deg;
        dinv[node] = rsqrtf((float)(deg + 1));
    } else {
        pdeg = 0;
    }
    red[t] = pdeg;
    __syncthreads();
    for (int off = 128; off > 0; off >>= 1) {
        if (t < off) red[t] += red[t + off];
        __syncthreads();
    }
    if (t == 0) pbsum[b] = red[0];
}

// exclusive scan of padded bucket sums -> pbase; set row_ptr[n]
__global__ void pscan(const int* __restrict__ pbsum, int* __restrict__ pbase,
                      int* __restrict__ row_ptr, int nb, int n) {
    __shared__ int s[512];
    int t = threadIdx.x;
    s[t] = (t < nb) ? pbsum[t] : 0;
    __syncthreads();
    for (int off = 1; off < 512; off <<= 1) {
        int add = (t >= off) ? s[t - off] : 0;
        __syncthreads();
        s[t] += add;
        __syncthreads();
    }
    if (t < nb) pbase[t] = (t == 0) ? 0 : s[t - 1];
    if (t == 0) {
        pbase[nb] = s[nb - 1];
        row_ptr[n] = s[nb - 1];
    }
}

// padded per-bucket CSR build: row_ptr (8-aligned rows), scatter src, dummy-fill pad slots
__global__ __launch_bounds__(256) void bucket_csr(const unsigned int* __restrict__ ebuf,
                                                  const int* __restrict__ bbase,
                                                  const int* __restrict__ pbase,
                                                  const int* __restrict__ degs,
                                                  int* __restrict__ row_ptr,
                                                  int* __restrict__ csr, int n) {
    __shared__ int lcur[256];
    __shared__ int lscan[256];
    int b = blockIdx.x, t = threadIdx.x;
    int beg = bbase[b], end = bbase[b + 1];
    int node = (b << BSHIFT) + t;
    int deg = (node < n) ? degs[node] : 0;
    int pdeg = (deg + 7) & ~7;
    lscan[t] = pdeg;
    __syncthreads();
    for (int off = 1; off < 256; off <<= 1) {
        int add = (t >= off) ? lscan[t - off] : 0;
        __syncthreads();
        lscan[t] += add;
        __syncthreads();
    }
    int rp = pbase[b] + lscan[t] - pdeg;  // exclusive
    if (node < n) row_ptr[node] = rp;
    lcur[t] = rp;
    __syncthreads();
    for (int i = beg + t; i < end; i += 256) {
        unsigned int p = ebuf[i];
        int pos = atomicAdd(&lcur[p >> 20], 1);
        csr[pos] = (int)(p & 0xFFFFFu);
    }
    __syncthreads();
    for (int j = deg; j < pdeg; j++) csr[rp + j] = n;  // dummy (zero row)
}

// ---------------- MFMA bf16 GEMM: out = A[N,128] @ W, B staged in LDS ----------------
// MODE 0: outB = bf16(dinv[r] * (A@W))  (pre-scaled rows for the aggregation)
// MODE 2: fused BN-folded classifier + output projection; bias2 (= bc) added to bias
template <int MODE, int AF32>
__global__ __launch_bounds__(256, 4) void gemm_k(const void* __restrict__ Avoid,
                                                 const unsigned short* __restrict__ WT,
                                                 const float* __restrict__ bias,
                                                 const float* __restrict__ bias2,
                                                 unsigned short* __restrict__ outB,
                                                 float* __restrict__ outF,
                                                 const float* __restrict__ Wr,
                                                 const float* __restrict__ br,
                                                 const float* __restrict__ dinvp, int n) {
    __shared__ unsigned short Ws[32 * 512];
    {
        for (int c = threadIdx.x; c < 2048; c += 256) {
            int f = c >> 6;
            int l = c & 63;
            int ks = f >> 3, ct = f & 7;
            int nn = ct * 16 + (l & 15);
            int kb = ks * 32 + (l >> 4) * 8;
            *(uint4*)(&Ws[c * 8]) = *(const uint4*)(&WT[nn * 128 + kb]);
        }
    }
    __syncthreads();
    const int wave = threadIdx.x >> 6;
    const int lane = threadIdx.x & 63;
    const int rowbase = blockIdx.x * 128 + wave * 32;
    const int m = lane & 15;
    const int kq = lane >> 4;  // 0..3

    floatx4 acc[2][8];
#pragma unroll
    for (int rt = 0; rt < 2; rt++)
#pragma unroll
        for (int ct = 0; ct < 8; ct++) acc[rt][ct] = (floatx4){0.f, 0.f, 0.f, 0.f};

    const int r0 = min(rowbase + m, n - 1);
    const int r1 = min(rowbase + 16 + m, n - 1);

#pragma unroll
    for (int ks = 0; ks < 4; ks++) {
        const int kb = ks * 32 + kq * 8;
        bf16x8 a0, a1;
        if (AF32) {
            const float* Af = (const float*)Avoid;
            float4 f00 = *(const float4*)(Af + (size_t)r0 * 128 + kb);
            float4 f01 = *(const float4*)(Af + (size_t)r0 * 128 + kb + 4);
            float4 f10 = *(const float4*)(Af + (size_t)r1 * 128 + kb);
            float4 f11 = *(const float4*)(Af + (size_t)r1 * 128 + kb + 4);
            ushort8 u0, u1;
            u0[0] = f2bf(f00.x); u0[1] = f2bf(f00.y); u0[2] = f2bf(f00.z); u0[3] = f2bf(f00.w);
            u0[4] = f2bf(f01.x); u0[5] = f2bf(f01.y); u0[6] = f2bf(f01.z); u0[7] = f2bf(f01.w);
            u1[0] = f2bf(f10.x); u1[1] = f2bf(f10.y); u1[2] = f2bf(f10.z); u1[3] = f2bf(f10.w);
            u1[4] = f2bf(f11.x); u1[5] = f2bf(f11.y); u1[6] = f2bf(f11.z); u1[7] = f2bf(f11.w);
            a0 = __builtin_bit_cast(bf16x8, u0);
            a1 = __builtin_bit_cast(bf16x8, u1);
        } else {
            const unsigned short* Ab = (const unsigned short*)Avoid;
            a0 = __builtin_bit_cast(bf16x8, *(const ushort8*)(Ab + (size_t)r0 * 128 + kb));
            a1 = __builtin_bit_cast(bf16x8, *(const ushort8*)(Ab + (size_t)r1 * 128 + kb));
        }
#pragma unroll
        for (int ct = 0; ct < 8; ct++) {
            bf16x8 bfr = __builtin_bit_cast(bf16x8,
                *(const ushort8*)(&Ws[(ks * 8 + ct) * 512 + lane * 8]));
            acc[0][ct] = __builtin_amdgcn_mfma_f32_16x16x32_bf16(a0, bfr, acc[0][ct], 0, 0, 0);
            acc[1][ct] = __builtin_amdgcn_mfma_f32_16x16x32_bf16(a1, bfr, acc[1][ct], 0, 0, 0);
        }
    }

    if (MODE == 0) {
#pragma unroll
        for (int rt = 0; rt < 2; rt++) {
#pragma unroll
            for (int i = 0; i < 4; i++) {
                int r = rowbase + rt * 16 + kq * 4 + i;
                if (r < n) {
                    float dv = dinvp[r];
#pragma unroll
                    for (int ct = 0; ct < 8; ct++) {
                        int col = ct * 16 + m;
                        outB[(size_t)r * 128 + col] = f2bf(acc[rt][ct][i] * dv);
                    }
                }
            }
        }
    } else {
        float bcv[8], wr0[8], wr1[8];
#pragma unroll
        for (int ct = 0; ct < 8; ct++) {
            int col = ct * 16 + m;
            bcv[ct] = bias[col] + bias2[col];
            float2 wv = ((const float2*)Wr)[col];
            wr0[ct] = wv.x;
            wr1[ct] = wv.y;
        }
        float br0 = br[0], br1 = br[1];
#pragma unroll
        for (int rt = 0; rt < 2; rt++) {
#pragma unroll
            for (int i = 0; i < 4; i++) {
                float p0 = 0.f, p1 = 0.f;
#pragma unroll
                for (int ct = 0; ct < 8; ct++) {
                    float v = fmaxf(acc[rt][ct][i] + bcv[ct], 0.f);
                    p0 = fmaf(v, wr0[ct], p0);
                    p1 = fmaf(v, wr1[ct], p1);
                }
#pragma unroll
                for (int mk = 1; mk < 16; mk <<= 1) {
                    p0 += __shfl_xor(p0, mk);
                    p1 += __shfl_xor(p1, mk);
                }
                int r = rowbase + rt * 16 + kq * 4 + i;
                if (m == 0 && r < n) ((float2*)outF)[r] = make_float2(p0 + br0, p1 + br1);
            }
        }
    }
}

// ---------------- CSR gather aggregation over pre-scaled h': 16 lanes/node ----------------
// agg[d] = relu( dinv[d] * ( sum_{s in N(d)} h'[s] + h'[d] ) + bias ),  h' = dinv_r * hW
// rows padded to x8 with dummy edges -> row N (zeros); 2x int4 index loads, prefetched.
// SESSION LEDGER (do not re-attempt without new HW evidence): pinned at per-CU vector-memory
// gather-path capacity (~0.19 sectors/cy/CU, 7.4 TB/s effective from cache hierarchy).
// Nulls: software MLP (r2,r3), L2-footprint halving (r5), asm counted-vmcnt pipeline
// (r6-r8, faults), XCD feature-slicing (r12: 3.5x FETCH from sector granularity, -137us).
#define ACC8(v)                                          \
    a[0] += bf2f_lo((v).x); a[1] += bf2f_hi((v).x);      \
    a[2] += bf2f_lo((v).y); a[3] += bf2f_hi((v).y);      \
    a[4] += bf2f_lo((v).z); a[5] += bf2f_hi((v).z);      \
    a[6] += bf2f_lo((v).w); a[7] += bf2f_hi((v).w);

__global__ __launch_bounds__(256) void agg_k(const unsigned short* __restrict__ hS,
                                             const int* __restrict__ csr,
                                             const int* __restrict__ row_ptr,
                                             const float* __restrict__ dinv,
                                             const float* __restrict__ bias,
                                             unsigned short* __restrict__ out, int n) {
    int node = blockIdx.x * 16 + (threadIdx.x >> 4);
    int t = threadIdx.x & 15;
    if (node >= n) return;
    const uint4* h4 = (const uint4*)hS;
    uint4 vs = h4[(size_t)node * 16 + t];  // self contribution, issued first
    int beg = row_ptr[node], pend = row_ptr[node + 1];
    float dd = dinv[node];

    float a[8];
    a[0] = bf2f_lo(vs.x); a[1] = bf2f_hi(vs.x);
    a[2] = bf2f_lo(vs.y); a[3] = bf2f_hi(vs.y);
    a[4] = bf2f_lo(vs.z); a[5] = bf2f_hi(vs.z);
    a[6] = bf2f_lo(vs.w); a[7] = bf2f_hi(vs.w);

    const int4* cp = (const int4*)(csr + beg);  // beg is multiple of 8 -> 16B aligned
    int nc = (pend - beg) >> 3;                 // chunks of 8 edges
    if (nc > 0) {
        int4 i0 = cp[0], i1 = cp[1];
        for (int k = 0; k < nc; k++) {
            uint4 v0 = h4[(size_t)(unsigned)i0.x * 16 + t];
            uint4 v1 = h4[(size_t)(unsigned)i0.y * 16 + t];
            uint4 v2 = h4[(size_t)(unsigned)i0.z * 16 + t];
            uint4 v3 = h4[(size_t)(unsigned)i0.w * 16 + t];
            uint4 v4 = h4[(size_t)(unsigned)i1.x * 16 + t];
            uint4 v5 = h4[(size_t)(unsigned)i1.y * 16 + t];
            uint4 v6 = h4[(size_t)(unsigned)i1.z * 16 + t];
            uint4 v7 = h4[(size_t)(unsigned)i1.w * 16 + t];
            int4 p0 = cp[2 * k + 2];  // prefetch next chunk's indices (csr has +16 slack)
            int4 p1 = cp[2 * k + 3];
            ACC8(v0); ACC8(v1); ACC8(v2); ACC8(v3);
            ACC8(v4); ACC8(v5); ACC8(v6); ACC8(v7);
            i0 = p0; i1 = p1;
        }
    }

    float4 b0 = ((const float4*)bias)[t * 2];
    float4 b1 = ((const float4*)bias)[t * 2 + 1];
    uint4 o;
    o.x = (unsigned int)f2bf(fmaxf(fmaf(dd, a[0], b0.x), 0.f)) |
          ((unsigned int)f2bf(fmaxf(fmaf(dd, a[1], b0.y), 0.f)) << 16);
    o.y = (unsigned int)f2bf(fmaxf(fmaf(dd, a[2], b0.z), 0.f)) |
          ((unsigned int)f2bf(fmaxf(fmaf(dd, a[3], b0.w), 0.f)) << 16);
    o.z = (unsigned int)f2bf(fmaxf(fmaf(dd, a[4], b1.x), 0.f)) |
          ((unsigned int)f2bf(fmaxf(fmaf(dd, a[5], b1.y), 0.f)) << 16);
    o.w = (unsigned int)f2bf(fmaxf(fmaf(dd, a[6], b1.z), 0.f)) |
          ((unsigned int)f2bf(fmaxf(fmaf(dd, a[7], b1.w), 0.f)) << 16);
    ((uint4*)out)[(size_t)node * 16 + t] = o;
}

// ---------------- BN stats (per-channel sum / sumsq) over bf16 h ----------------
__global__ __launch_bounds__(256) void bn_stats(const unsigned short* __restrict__ h,
                                                float* __restrict__ gsum,
                                                float* __restrict__ gsumsq, int n) {
    __shared__ float red[4][256];
    int l = threadIdx.x & 63;
    int rs = threadIdx.x >> 6;
    float s0 = 0.f, s1 = 0.f, q0 = 0.f, q1 = 0.f;
    for (int r = blockIdx.x * 4 + rs; r < n; r += gridDim.x * 4) {
        unsigned int v = *(const unsigned int*)(h + (size_t)r * 128 + l * 2);
        float a = bf2f_lo(v), b = bf2f_hi(v);
        s0 += a;
        s1 += b;
        q0 = fmaf(a, a, q0);
        q1 = fmaf(b, b, q1);
    }
    red[0][threadIdx.x] = s0;
    red[1][threadIdx.x] = s1;
    red[2][threadIdx.x] = q0;
    red[3][threadIdx.x] = q1;
    __syncthreads();
    if (threadIdx.x < 64) {
        float S0 = 0.f, S1 = 0.f, Q0 = 0.f, Q1 = 0.f;
#pragma unroll
        for (int j = 0; j < 4; j++) {
            S0 += red[0][j * 64 + l];
            S1 += red[1][j * 64 + l];
            Q0 += red[2][j * 64 + l];
            Q1 += red[3][j * 64 + l];
        }
        atomicAdd(&gsum[2 * l + 0], S0);
        atomicAdd(&gsum[2 * l + 1], S1);
        atomicAdd(&gsumsq[2 * l + 0], Q0);
        atomicAdd(&gsumsq[2 * l + 1], Q1);
    }
}

// ---------------- fused BN-finalize + fold into Wc ----------------
__global__ __launch_bounds__(256) void wcfold(const float* __restrict__ Wc,
                                              const float* __restrict__ gsum,
                                              const float* __restrict__ gsumsq,
                                              const float* __restrict__ gamma,
                                              const float* __restrict__ beta,
                                              unsigned short* __restrict__ WcT,
                                              float* __restrict__ bcP, float invN) {
    __shared__ float scS[128], shS[128];
    if (threadIdx.x < 128) {
        int j = threadIdx.x;
        float mu = gsum[j] * invN;
        float var = gsumsq[j] * invN - mu * mu;
        float sc = gamma[j] * rsqrtf(var + 1e-5f);
        scS[j] = sc;
        shS[j] = beta[j] - mu * sc;
    }
    __syncthreads();
    int idx = blockIdx.x * 256 + threadIdx.x;  // 16384; j inner -> coalesced Wc reads
    int j = idx & 127, k = idx >> 7;
    float w = Wc[k * 128 + j];
    WcT[j * 128 + k] = f2bf(scS[k] * w);
    atomicAdd(&bcP[j], shS[k] * w);
}

// ---------------- host ----------------

extern "C" void kernel_launch(void* const* d_in, const int* in_sizes, int n_in,
                              void* d_out, int out_size, void* d_ws, size_t ws_size,
                              hipStream_t stream) {
    const float* x = (const float*)d_in[0];
    const int* ei = (const int*)d_in[1];
    const float* W1 = (const float*)d_in[2];
    const float* b1 = (const float*)d_in[3];
    const float* W2 = (const float*)d_in[4];
    const float* b2 = (const float*)d_in[5];
    const float* W3 = (const float*)d_in[6];
    const float* b3 = (const float*)d_in[7];
    const float* gamma = (const float*)d_in[8];
    const float* beta = (const float*)d_in[9];
    const float* Wc = (const float*)d_in[10];
    const float* bc = (const float*)d_in[11];
    const float* Wr = (const float*)d_in[12];
    const float* br = (const float*)d_in[13];
    float* out = (float*)d_out;

    const int N = in_sizes[0] / DHC;
    const int E = in_sizes[1] / 2;
    const int* srcIdx = ei;
    const int* dstIdx = ei + E;
    const int NB = (N + BSIZE - 1) >> BSHIFT;

    char* w = (char*)d_ws;
    size_t off = 0;
    auto alloc = [&](size_t bytes) -> void* {
        void* p = w + off;
        off += (bytes + 255) & ~(size_t)255;
        return p;
    };
    // +1 dummy row (zeros) on each activation buffer for padded edges
    unsigned short* bufA = (unsigned short*)alloc((size_t)(N + 1) * DHC * 2);
    unsigned short* bufB = (unsigned short*)alloc((size_t)(N + 1) * DHC * 2);
    unsigned int* ebuf = (unsigned int*)alloc((size_t)E * 4);
    // padded CSR: up to E + 7 per node, +16 ints slack
    int* csr_src = (int*)alloc(((size_t)E + 8 * (size_t)N + 16) * 4);
    int* row_ptr = (int*)alloc((size_t)(N + 1) * 4);
    float* dinv = (float*)alloc((size_t)N * 4);
    int* degs = (int*)alloc((size_t)N * 4);
    // zeroed region: bcount[512] ++ stats[256] ++ bcP[128] — one memset
    int* bcount = (int*)alloc(512 * 4 + 256 * 4 + 128 * 4);
    float* stats = (float*)(bcount + 512);
    float* gsum = stats;
    float* gsumsq = stats + 128;
    float* bcP = stats + 256;
    int* bbase = (int*)alloc(513 * 4);
    int* bcur = (int*)alloc(512 * 4);
    int* pbsum = (int*)alloc(512 * 4);
    int* pbase = (int*)alloc(513 * 4);
    unsigned short* WTall = (unsigned short*)alloc((size_t)3 * 16384 * 2);
    unsigned short* WT1 = WTall;
    unsigned short* WT2 = WTall + 16384;
    unsigned short* WT3 = WTall + 32768;
    unsigned short* WcT = (unsigned short*)alloc(16384 * 2);
    (void)ws_size; (void)n_in; (void)out_size;

    hipMemsetAsync(bcount, 0, 512 * 4 + 256 * 4 + 128 * 4, stream);

    const int EB = (E + 4095) / 4096;
    bucket_hist<<<EB + 192, 256, 0, stream>>>(dstIdx, bcount, E, EB, W1, W2, W3, WTall,
                                              bufA + (size_t)N * DHC, bufB + (size_t)N * DHC);
    bucket_scan<<<1, 512, 0, stream>>>(bcount, bbase, bcur, NB, E);
    bucket_scatter<<<EB, 256, 0, stream>>>(srcIdx, dstIdx, bcur, ebuf, E);
    bucket_dega<<<NB, 256, 0, stream>>>(ebuf, bbase, degs, pbsum, dinv, N);
    pscan<<<1, 512, 0, stream>>>(pbsum, pbase, row_ptr, NB, N);
    bucket_csr<<<NB, 256, 0, stream>>>(ebuf, bbase, pbase, degs, row_ptr, csr_src, N);

    const int gemmBlocks = (N + 127) / 128;
    const int aggBlocks = (N + 15) / 16;

    // layer 1 (A = x fp32, converted in-flight); gemm writes dinv-prescaled rows
    gemm_k<0, 1><<<gemmBlocks, 256, 0, stream>>>(x, WT1, nullptr, nullptr, bufB, nullptr, nullptr, nullptr, dinv, N);
    agg_k<<<aggBlocks, 256, 0, stream>>>(bufB, csr_src, row_ptr, dinv, b1, bufA, N);
    // layer 2
    gemm_k<0, 0><<<gemmBlocks, 256, 0, stream>>>(bufA, WT2, nullptr, nullptr, bufB, nullptr, nullptr, nullptr, dinv, N);
    agg_k<<<aggBlocks, 256, 0, stream>>>(bufB, csr_src, row_ptr, dinv, b2, bufA, N);
    // layer 3
    gemm_k<0, 0><<<gemmBlocks, 256, 0, stream>>>(bufA, WT3, nullptr, nullptr, bufB, nullptr, nullptr, nullptr, dinv, N);
    agg_k<<<aggBlocks, 256, 0, stream>>>(bufB, csr_src, row_ptr, dinv, b3, bufA, N);

    // batchnorm stats + fused finalize/fold + classifier GEMM fused with output projection
    bn_stats<<<256, 256, 0, stream>>>(bufA, gsum, gsumsq, N);
    wcfold<<<64, 256, 0, stream>>>(Wc, gsum, gsumsq, gamma, beta, WcT, bcP, 1.0f / (float)N);
    gemm_k<2, 0><<<gemmBlocks, 256, 0, stream>>>(bufA, WcT, bcP, bc, nullptr, out, Wr, br, dinv, N);
}